// Round 6
// baseline (380.847 us; speedup 1.0000x reference)
//
#include <hip/hip_runtime.h>
#include <hip/hip_bf16.h>

#define BATCH 32
#define E 256
#define V 32000
#define NSTEP 128
#define M_TOTAL (BATCH * NSTEP)   // 4096
#define BM 128
#define BN 128
#define NBN (V / BN)              // 250
#define NPART (4 * NBN)           // 1000 partial stripes

typedef __attribute__((ext_vector_type(4))) float f32x4;
typedef __attribute__((ext_vector_type(8))) short s16x8;
typedef __attribute__((ext_vector_type(2))) unsigned int u32x2;

static __device__ __forceinline__ short f2bf(float v) {
    __hip_bfloat16 h = __float2bfloat16(v);
    return *reinterpret_cast<short*>(&h);
}

// fp8 e4m3 (OCP) conversion via HW packed-convert instruction.
static __device__ __forceinline__ unsigned char f2fp8(float v) {
    int p = __builtin_amdgcn_cvt_pk_fp8_f32(v, v, 0, false);
    return (unsigned char)(p & 0xff);
}

static __device__ __forceinline__ void gload_lds16(const void* g, void* l) {
    __builtin_amdgcn_global_load_lds((const __attribute__((address_space(1))) void*)g,
                                     (__attribute__((address_space(3))) void*)l,
                                     16, 0, 0);
}

// DPP row_ror reduction within each 16-lane row (VALU pipe, no LDS traffic).
template<int CTRL>
static __device__ __forceinline__ float dpp_add(float v) {
    int i = __builtin_amdgcn_update_dpp(0, __builtin_bit_cast(int, v), CTRL, 0xF, 0xF, false);
    return v + __builtin_bit_cast(float, i);
}
static __device__ __forceinline__ float row16_sum(float v) {
    v = dpp_add<0x121>(v);
    v = dpp_add<0x122>(v);
    v = dpp_add<0x124>(v);
    v = dpp_add<0x128>(v);
    return v;
}

// ---------------------------------------------------------------------------
// Kernel 1 (merged): blocks 0..31 = RNN trajectory (bf16 MFMA, trans-in-regs,
// fp32 scale recursion); blocks 32.. = vocab_w transpose+convert to fp8.
// ---------------------------------------------------------------------------
__global__ __launch_bounds__(512, 2) void traj_transpose_kernel(
        const float* __restrict__ latent, const int* __restrict__ zi,
        const float* __restrict__ w,
        unsigned char* __restrict__ zsb8, unsigned char* __restrict__ wt8) {
    __shared__ float tile[64][65];           // transpose path
    __shared__ __align__(16) short zsh[E];   // traj: z as bf16 (A-frag layout)
    __shared__ __align__(16) float red[16];  // traj: per-wave s / s2 partials

    const int tid = threadIdx.x;

    if (blockIdx.x >= BATCH) {
        // ---- transpose + convert: vocab_w (E x V f32) -> wt8 (V x E fp8) ----
        const int bb = blockIdx.x - BATCH;   // 0..1999
        const int k0 = (bb & 3) * 64;
        const int n0 = (bb >> 2) * 64;
        const int c  = tid & 63;
        const int r8 = tid >> 6;             // 0..7
        #pragma unroll
        for (int r = r8; r < 64; r += 8)
            tile[r][c] = w[(size_t)(k0 + r) * V + n0 + c];
        __syncthreads();
        #pragma unroll
        for (int r = r8; r < 64; r += 8)
            wt8[(size_t)(n0 + r) * E + k0 + c] = f2fp8(tile[c][r]);
        return;
    }

    // ---- trajectory path: one batch per block, 8 waves ----
    const int b    = blockIdx.x;
    const int lane = tid & 63;
    const int wv   = tid >> 6;       // 0..7, owns cols [32wv, 32wv+32)
    const int lm   = lane & 15;
    const int g    = lane >> 4;      // k-group within fragment
    const float* tr = latent + (size_t)zi[b] * (E * E);

    // B-fragments in registers: B[n][k] = trans[k][n], bf16. 2 tiles x 8 kk.
    s16x8 bfrag[2][8];
    #pragma unroll
    for (int nt = 0; nt < 2; ++nt)
        #pragma unroll
        for (int kk = 0; kk < 8; ++kk) {
            s16x8 fr;
            #pragma unroll
            for (int j = 0; j < 8; ++j)
                fr[j] = f2bf(tr[(size_t)(kk * 32 + g * 8 + j) * E + wv * 32 + nt * 16 + lm]);
            bfrag[nt][kk] = fr;
        }

    // z0 = trans[0, :]
    if (tid < E) zsh[tid] = f2bf(tr[tid]);

    // scale_0 from std(z0)
    {
        float v = (tid < E) ? tr[tid] : 0.f;
        float a = row16_sum(v), a2 = row16_sum(v * v);
        a  += __shfl_xor(a, 16);  a2 += __shfl_xor(a2, 16);
        a  += __shfl_xor(a, 32);  a2 += __shfl_xor(a2, 32);
        if (lane == 0) { red[wv] = a; red[8 + wv] = a2; }
    }
    __syncthreads();

    float scale;
    {
        f32x4 p0 = *(const f32x4*)&red[0], p1 = *(const f32x4*)&red[4];
        f32x4 q0 = *(const f32x4*)&red[8], q1 = *(const f32x4*)&red[12];
        float ts  = (p0[0]+p0[1]+p0[2]+p0[3]) + (p1[0]+p1[1]+p1[2]+p1[3]);
        float ts2 = (q0[0]+q0[1]+q0[2]+q0[3]) + (q1[0]+q1[1]+q1[2]+q1[3]);
        float var = fmaxf((ts2 - ts * ts * (1.0f / 256.0f)) * (1.0f / 255.0f), 0.f);
        scale = 0.113f / (1e-5f + sqrtf(var));
    }
    __syncthreads();

    for (int t = 0; t < NSTEP; ++t) {
        s16x8 a[8];
        #pragma unroll
        for (int kk = 0; kk < 8; ++kk)
            a[kk] = *(const s16x8*)((const char*)zsh + kk * 64 + g * 16);

        f32x4 acc0 = {}, acc1 = {};
        #pragma unroll
        for (int kk = 0; kk < 8; ++kk) {
            acc0 = __builtin_amdgcn_mfma_f32_16x16x32_bf16(a[kk], bfrag[0][kk], acc0, 0, 0, 0);
            acc1 = __builtin_amdgcn_mfma_f32_16x16x32_bf16(a[kk], bfrag[1][kk], acc1, 0, 0, 0);
        }

        float u  = row16_sum(acc0[0] + acc1[0]);
        float u2 = row16_sum(acc0[0] * acc0[0] + acc1[0] * acc1[0]);
        if (lane == 0) { red[wv] = u; red[8 + wv] = u2; }
        __syncthreads();

        f32x4 p0 = *(const f32x4*)&red[0], p1 = *(const f32x4*)&red[4];
        f32x4 q0 = *(const f32x4*)&red[8], q1 = *(const f32x4*)&red[12];
        float ts  = (p0[0]+p0[1]+p0[2]+p0[3]) + (p1[0]+p1[1]+p1[2]+p1[3]);
        float ts2 = (q0[0]+q0[1]+q0[2]+q0[3]) + (q1[0]+q1[1]+q1[2]+q1[3]);
        float var = fmaxf((ts2 - ts * ts * (1.0f / 256.0f)) * (1.0f / 255.0f), 0.f);
        float stdr = sqrtf(var);

        float e0 = scale * acc0[0], e1 = scale * acc1[0];
        if (g == 0) {
            zsh[wv * 32 + lm]      = f2bf(e0);
            zsh[wv * 32 + 16 + lm] = f2bf(e1);
            unsigned char* zr = zsb8 + ((size_t)b * NSTEP + t) * E + wv * 32;
            zr[lm]      = f2fp8(e0);
            zr[16 + lm] = f2fp8(e1);
        }
        scale = 0.113f / (1e-5f + scale * stdr);
        __syncthreads();
    }
}

// ---------------------------------------------------------------------------
// Kernel 2: fp8 GEMM (4096 x 32000 x 256) + fused LSE partials.
// 128x128 tile, 8 waves (2 wr x 4 wc), wave tile 64x32. A (64 rows x K=256
// fp8) fully register-resident (64 VGPR); B panel 32 KB LDS with 16B-slot
// rotate layout (conflict-lite, gload_lds-compatible). One barrier total;
// 2 blocks/CU so staging hides under the sibling block's compute.
// ---------------------------------------------------------------------------
__global__ __launch_bounds__(512, 4) void gemm_lse_kernel(const unsigned char* __restrict__ zsb8,
                                                          const unsigned char* __restrict__ wt8,
                                                          const float* __restrict__ vb,
                                                          const int* __restrict__ y,
                                                          float* __restrict__ partial,
                                                          float* __restrict__ logit_y) {
    __shared__ unsigned char bpan[BN * E];   // 32 KB fp8

    const int tid  = threadIdx.x;
    const int lane = tid & 63;
    const int w    = tid >> 6;        // 0..7

    // Bijective XCD remap, bm-fast (8000 = 8 * 1000, 32 bm per bn).
    const int bid = blockIdx.x;
    const int gg  = (bid & 7) * 1000 + (bid >> 3);
    const int bn  = gg >> 5;                  // 0..249
    const int bm  = gg & 31;                  // 0..31
    const int n0  = bn * BN;
    const int m0  = bm * BM;

    // ---- stage B panel: LDS 16B-slot s' = (s + row) & 15 (rotate layout) ----
    #pragma unroll
    for (int i = 0; i < 4; ++i) {
        const int c     = i * 512 + tid;      // 16B chunk id, 0..2047
        const int row   = c >> 4;             // local n row (256 B/row)
        const int slot  = c & 15;
        const int gslot = (slot - row) & 15;
        gload_lds16(wt8 + (size_t)(n0 + row) * E + gslot * 16,
                    (char*)bpan + c * 16);
    }

    const int wr = w >> 2, wc = w & 3;        // 2 x 4 wave grid
    const int lm = lane & 15, lk = lane >> 4;
    const int mw = m0 + wr * 64;

    // ---- A panel into registers: 64 rows x 256 k (fp8) per wave ----
    u32x2 areg[4][8];
    #pragma unroll
    for (int rt = 0; rt < 4; ++rt)
        #pragma unroll
        for (int kk = 0; kk < 8; ++kk)
            areg[rt][kk] = *(const u32x2*)(zsb8 + (size_t)(mw + rt * 16 + lm) * E + kk * 32 + lk * 8);

    __syncthreads();   // B resident, A in regs

    // ---- K loop: pure ds_read + MFMA ----
    f32x4 acc[4][2] = {};   // [rt][nt]
    #pragma unroll
    for (int kk = 0; kk < 8; ++kk) {
        #pragma unroll
        for (int nt = 0; nt < 2; ++nt) {
            const int row_n = wc * 32 + nt * 16 + lm;
            const int slot  = (kk * 2 + (lk >> 1) + row_n) & 15;
            u32x2 bf = *(const u32x2*)(bpan + row_n * 256 + slot * 16 + (lk & 1) * 8);
            const long long bl = __builtin_bit_cast(long long, bf);
            #pragma unroll
            for (int rt = 0; rt < 4; ++rt)
                acc[rt][nt] = __builtin_amdgcn_mfma_f32_16x16x32_fp8_fp8(
                    __builtin_bit_cast(long long, areg[rt][kk]), bl, acc[rt][nt], 0, 0, 0);
        }
    }

    // ---- epilogue: bias, exp-rowsum over this wave's 32 cols, target gather ----
    const int cr = lane >> 4;
    #pragma unroll
    for (int rt = 0; rt < 4; ++rt) {
        const int rowbase = mw + rt * 16 + cr * 4;
        int yr[4];
        #pragma unroll
        for (int r = 0; r < 4; ++r) yr[r] = y[rowbase + r];

        float rs[4] = {0.f, 0.f, 0.f, 0.f};
        #pragma unroll
        for (int nt = 0; nt < 2; ++nt) {
            const int n_g  = n0 + wc * 32 + nt * 16 + lm;
            const float bias = vb[n_g];
            #pragma unroll
            for (int r = 0; r < 4; ++r) {
                float logit = acc[rt][nt][r] + bias;
                if (n_g == yr[r]) logit_y[rowbase + r] = logit;
                rs[r] += __expf(logit);
            }
        }
        #pragma unroll
        for (int r = 0; r < 4; ++r) rs[r] = row16_sum(rs[r]);
        if (lm == 0) {
            #pragma unroll
            for (int r = 0; r < 4; ++r)
                partial[(size_t)(bn * 4 + wc) * M_TOTAL + rowbase + r] = rs[r];
        }
    }
}

// ---------------------------------------------------------------------------
// Kernel 3: yp[row] = logit_y[row] - log(sum over NPART partials)
// ---------------------------------------------------------------------------
__global__ __launch_bounds__(256) void finalize_kernel(const float* __restrict__ partial,
                                                       const float* __restrict__ logit_y,
                                                       float* __restrict__ out) {
    __shared__ float s[16][17];
    const int tid = threadIdx.x;
    const int jp = tid >> 4, r = tid & 15;
    const int rowbase = blockIdx.x * 16;

    float acc = 0.f;
    for (int j = jp; j < NPART; j += 16)
        acc += partial[(size_t)j * M_TOTAL + rowbase + r];
    s[jp][r] = acc;
    __syncthreads();

    if (tid < 16) {
        float t = 0.f;
        #pragma unroll
        for (int k = 0; k < 16; ++k) t += s[k][tid];
        out[rowbase + tid] = logit_y[rowbase + tid] - logf(t);
    }
}

// ---------------------------------------------------------------------------
extern "C" void kernel_launch(void* const* d_in, const int* in_sizes, int n_in,
                              void* d_out, int out_size, void* d_ws, size_t ws_size,
                              hipStream_t stream) {
    const float* latent  = (const float*)d_in[0];
    const float* vocab_w = (const float*)d_in[1];
    const float* vocab_b = (const float*)d_in[2];
    const int*   zi      = (const int*)d_in[3];
    const int*   y       = (const int*)d_in[4];
    float* out = (float*)d_out;

    char* ws = (char*)d_ws;
    float*         logit_y = (float*)(ws);                         // 16 KB
    float*         partial = (float*)(ws + 16384);                 // 1000*4096*4 = 16 MB
    unsigned char* zsb8    = (unsigned char*)(ws + 16384 + 16777216);            // 1 MB
    unsigned char* wt8     = (unsigned char*)(ws + 16384 + 16777216 + 1048576);  // 8 MB

    hipLaunchKernelGGL(traj_transpose_kernel, dim3(BATCH + 4 * (V / 64)), dim3(512), 0, stream,
                       latent, zi, vocab_w, zsb8, wt8);
    hipLaunchKernelGGL(gemm_lse_kernel, dim3(32 * NBN), dim3(512), 0, stream,
                       zsb8, wt8, vocab_b, y, partial, logit_y);
    hipLaunchKernelGGL(finalize_kernel, dim3(M_TOTAL / 16), dim3(256), 0, stream,
                       partial, logit_y, out);
}

// Round 7
// 196.659 us; speedup vs baseline: 1.9366x; 1.9366x over previous
//
#include <hip/hip_runtime.h>
#include <hip/hip_bf16.h>

#define BATCH 32
#define E 256
#define V 32000
#define NSTEP 128
#define M_TOTAL (BATCH * NSTEP)   // 4096
#define BM 128
#define BN 128
#define NBN (V / BN)              // 250
#define NPART (4 * NBN)           // 1000 partial stripes

typedef __attribute__((ext_vector_type(4))) float f32x4;
typedef __attribute__((ext_vector_type(8))) short s16x8;
typedef __attribute__((ext_vector_type(2))) unsigned int u32x2;

static __device__ __forceinline__ short f2bf(float v) {
    __hip_bfloat16 h = __float2bfloat16(v);
    return *reinterpret_cast<short*>(&h);
}

// fp8 e4m3 (OCP) conversion via HW packed-convert instruction.
static __device__ __forceinline__ unsigned char f2fp8(float v) {
    int p = __builtin_amdgcn_cvt_pk_fp8_f32(v, v, 0, false);
    return (unsigned char)(p & 0xff);
}

static __device__ __forceinline__ void gload_lds16(const void* g, void* l) {
    __builtin_amdgcn_global_load_lds((const __attribute__((address_space(1))) void*)g,
                                     (__attribute__((address_space(3))) void*)l,
                                     16, 0, 0);
}

// DPP row_ror reduction within each 16-lane row (VALU pipe, no LDS traffic).
template<int CTRL>
static __device__ __forceinline__ float dpp_add(float v) {
    int i = __builtin_amdgcn_update_dpp(0, __builtin_bit_cast(int, v), CTRL, 0xF, 0xF, false);
    return v + __builtin_bit_cast(float, i);
}
static __device__ __forceinline__ float row16_sum(float v) {
    v = dpp_add<0x121>(v);
    v = dpp_add<0x122>(v);
    v = dpp_add<0x124>(v);
    v = dpp_add<0x128>(v);
    return v;
}

// ---------------------------------------------------------------------------
// Kernel 1 (merged): blocks 0..31 = RNN trajectory (bf16 MFMA, trans-in-regs,
// fp32 scale recursion); blocks 32.. = vocab_w transpose+convert to fp8.
// ---------------------------------------------------------------------------
__global__ __launch_bounds__(512, 2) void traj_transpose_kernel(
        const float* __restrict__ latent, const int* __restrict__ zi,
        const float* __restrict__ w,
        unsigned char* __restrict__ zsb8, unsigned char* __restrict__ wt8) {
    __shared__ float tile[64][65];           // transpose path
    __shared__ __align__(16) short zsh[E];   // traj: z as bf16 (A-frag layout)
    __shared__ __align__(16) float red[16];  // traj: per-wave s / s2 partials

    const int tid = threadIdx.x;

    if (blockIdx.x >= BATCH) {
        // ---- transpose + convert: vocab_w (E x V f32) -> wt8 (V x E fp8) ----
        const int bb = blockIdx.x - BATCH;   // 0..1999
        const int k0 = (bb & 3) * 64;
        const int n0 = (bb >> 2) * 64;
        const int c  = tid & 63;
        const int r8 = tid >> 6;             // 0..7
        #pragma unroll
        for (int r = r8; r < 64; r += 8)
            tile[r][c] = w[(size_t)(k0 + r) * V + n0 + c];
        __syncthreads();
        #pragma unroll
        for (int r = r8; r < 64; r += 8)
            wt8[(size_t)(n0 + r) * E + k0 + c] = f2fp8(tile[c][r]);
        return;
    }

    // ---- trajectory path: one batch per block, 8 waves ----
    const int b    = blockIdx.x;
    const int lane = tid & 63;
    const int wv   = tid >> 6;       // 0..7, owns cols [32wv, 32wv+32)
    const int lm   = lane & 15;
    const int g    = lane >> 4;      // k-group within fragment
    const float* tr = latent + (size_t)zi[b] * (E * E);

    // B-fragments in registers: B[n][k] = trans[k][n], bf16. 2 tiles x 8 kk.
    s16x8 bfrag[2][8];
    #pragma unroll
    for (int nt = 0; nt < 2; ++nt)
        #pragma unroll
        for (int kk = 0; kk < 8; ++kk) {
            s16x8 fr;
            #pragma unroll
            for (int j = 0; j < 8; ++j)
                fr[j] = f2bf(tr[(size_t)(kk * 32 + g * 8 + j) * E + wv * 32 + nt * 16 + lm]);
            bfrag[nt][kk] = fr;
        }

    // z0 = trans[0, :]
    if (tid < E) zsh[tid] = f2bf(tr[tid]);

    // scale_0 from std(z0)
    {
        float v = (tid < E) ? tr[tid] : 0.f;
        float a = row16_sum(v), a2 = row16_sum(v * v);
        a  += __shfl_xor(a, 16);  a2 += __shfl_xor(a2, 16);
        a  += __shfl_xor(a, 32);  a2 += __shfl_xor(a2, 32);
        if (lane == 0) { red[wv] = a; red[8 + wv] = a2; }
    }
    __syncthreads();

    float scale;
    {
        f32x4 p0 = *(const f32x4*)&red[0], p1 = *(const f32x4*)&red[4];
        f32x4 q0 = *(const f32x4*)&red[8], q1 = *(const f32x4*)&red[12];
        float ts  = (p0[0]+p0[1]+p0[2]+p0[3]) + (p1[0]+p1[1]+p1[2]+p1[3]);
        float ts2 = (q0[0]+q0[1]+q0[2]+q0[3]) + (q1[0]+q1[1]+q1[2]+q1[3]);
        float var = fmaxf((ts2 - ts * ts * (1.0f / 256.0f)) * (1.0f / 255.0f), 0.f);
        scale = 0.113f / (1e-5f + sqrtf(var));
    }
    __syncthreads();

    for (int t = 0; t < NSTEP; ++t) {
        s16x8 a[8];
        #pragma unroll
        for (int kk = 0; kk < 8; ++kk)
            a[kk] = *(const s16x8*)((const char*)zsh + kk * 64 + g * 16);

        f32x4 acc0 = {}, acc1 = {};
        #pragma unroll
        for (int kk = 0; kk < 8; ++kk) {
            acc0 = __builtin_amdgcn_mfma_f32_16x16x32_bf16(a[kk], bfrag[0][kk], acc0, 0, 0, 0);
            acc1 = __builtin_amdgcn_mfma_f32_16x16x32_bf16(a[kk], bfrag[1][kk], acc1, 0, 0, 0);
        }

        float u  = row16_sum(acc0[0] + acc1[0]);
        float u2 = row16_sum(acc0[0] * acc0[0] + acc1[0] * acc1[0]);
        if (lane == 0) { red[wv] = u; red[8 + wv] = u2; }
        __syncthreads();

        f32x4 p0 = *(const f32x4*)&red[0], p1 = *(const f32x4*)&red[4];
        f32x4 q0 = *(const f32x4*)&red[8], q1 = *(const f32x4*)&red[12];
        float ts  = (p0[0]+p0[1]+p0[2]+p0[3]) + (p1[0]+p1[1]+p1[2]+p1[3]);
        float ts2 = (q0[0]+q0[1]+q0[2]+q0[3]) + (q1[0]+q1[1]+q1[2]+q1[3]);
        float var = fmaxf((ts2 - ts * ts * (1.0f / 256.0f)) * (1.0f / 255.0f), 0.f);
        float stdr = sqrtf(var);

        float e0 = scale * acc0[0], e1 = scale * acc1[0];
        if (g == 0) {
            zsh[wv * 32 + lm]      = f2bf(e0);
            zsh[wv * 32 + 16 + lm] = f2bf(e1);
            unsigned char* zr = zsb8 + ((size_t)b * NSTEP + t) * E + wv * 32;
            zr[lm]      = f2fp8(e0);
            zr[16 + lm] = f2fp8(e1);
        }
        scale = 0.113f / (1e-5f + scale * stdr);
        __syncthreads();
    }
}

// ---------------------------------------------------------------------------
// Kernel 2: fp8 GEMM (4096 x 32000 x 256) + fused LSE partials.
// BOTH panels in LDS (A 32 KB + B 32 KB = 64 KB -> 2 blocks/CU), fp8 e4m3.
// 8 waves (2 wr x 4 wc), wave tile 64x32, acc = 32 VGPR -> no spill risk.
// 16B-slot rotate layout on both panels (bank-spread, gload_lds-compatible).
// One barrier total; sibling block's compute hides this block's staging.
// ---------------------------------------------------------------------------
__global__ __launch_bounds__(512, 4) void gemm_lse_kernel(const unsigned char* __restrict__ zsb8,
                                                          const unsigned char* __restrict__ wt8,
                                                          const float* __restrict__ vb,
                                                          const int* __restrict__ y,
                                                          float* __restrict__ partial,
                                                          float* __restrict__ logit_y) {
    __shared__ unsigned char apan[BM * E];   // 32 KB fp8
    __shared__ unsigned char bpan[BN * E];   // 32 KB fp8

    const int tid  = threadIdx.x;
    const int lane = tid & 63;
    const int w    = tid >> 6;        // 0..7

    // Bijective XCD remap, bm-fast (8000 = 8 * 1000, 32 bm per bn).
    const int bid = blockIdx.x;
    const int gg  = (bid & 7) * 1000 + (bid >> 3);
    const int bn  = gg >> 5;                  // 0..249
    const int bm  = gg & 31;                  // 0..31
    const int n0  = bn * BN;
    const int m0  = bm * BM;

    // ---- stage panels: LDS[row][slot] = G[row][(slot-row)&15], 16B slots ----
    #pragma unroll
    for (int i = 0; i < 4; ++i) {
        const int c     = i * 512 + tid;      // 16B chunk id, 0..2047
        const int row   = c >> 4;             // local row (256 B/row)
        const int slot  = c & 15;
        const int gslot = (slot - row) & 15;
        gload_lds16(zsb8 + (size_t)(m0 + row) * E + gslot * 16,
                    (char*)apan + c * 16);
    }
    #pragma unroll
    for (int i = 0; i < 4; ++i) {
        const int c     = i * 512 + tid;
        const int row   = c >> 4;
        const int slot  = c & 15;
        const int gslot = (slot - row) & 15;
        gload_lds16(wt8 + (size_t)(n0 + row) * E + gslot * 16,
                    (char*)bpan + c * 16);
    }

    const int wr = w >> 2, wc = w & 3;        // 2 x 4 wave grid
    const int lm = lane & 15, lk = lane >> 4;

    __syncthreads();   // both panels resident (syncthreads drains vmcnt)

    // ---- K loop: pure ds_read_b64 + MFMA ----
    f32x4 acc[4][2] = {};   // [rt][nt]
    #pragma unroll
    for (int kk = 0; kk < 8; ++kk) {
        const int sbase = kk * 2 + (lk >> 1);
        const int half  = (lk & 1) * 8;
        long long afr[4];
        #pragma unroll
        for (int rt = 0; rt < 4; ++rt) {
            const int row_a = wr * 64 + rt * 16 + lm;
            const int slot  = (sbase + row_a) & 15;
            afr[rt] = *(const long long*)(apan + row_a * 256 + slot * 16 + half);
        }
        #pragma unroll
        for (int nt = 0; nt < 2; ++nt) {
            const int row_n = wc * 32 + nt * 16 + lm;
            const int slot  = (sbase + row_n) & 15;
            const long long bl = *(const long long*)(bpan + row_n * 256 + slot * 16 + half);
            #pragma unroll
            for (int rt = 0; rt < 4; ++rt)
                acc[rt][nt] = __builtin_amdgcn_mfma_f32_16x16x32_fp8_fp8(afr[rt], bl, acc[rt][nt], 0, 0, 0);
        }
    }

    // ---- epilogue: bias, exp-rowsum over this wave's 32 cols, target gather ----
    const int cr = lane >> 4;
    #pragma unroll
    for (int rt = 0; rt < 4; ++rt) {
        const int rowbase = m0 + wr * 64 + rt * 16 + cr * 4;
        int yr[4];
        #pragma unroll
        for (int r = 0; r < 4; ++r) yr[r] = y[rowbase + r];

        float rs[4] = {0.f, 0.f, 0.f, 0.f};
        #pragma unroll
        for (int nt = 0; nt < 2; ++nt) {
            const int n_g  = n0 + wc * 32 + nt * 16 + lm;
            const float bias = vb[n_g];
            #pragma unroll
            for (int r = 0; r < 4; ++r) {
                float logit = acc[rt][nt][r] + bias;
                if (n_g == yr[r]) logit_y[rowbase + r] = logit;
                rs[r] += __expf(logit);
            }
        }
        #pragma unroll
        for (int r = 0; r < 4; ++r) rs[r] = row16_sum(rs[r]);
        if (lm == 0) {
            #pragma unroll
            for (int r = 0; r < 4; ++r)
                partial[(size_t)(bn * 4 + wc) * M_TOTAL + rowbase + r] = rs[r];
        }
    }
}

// ---------------------------------------------------------------------------
// Kernel 3: yp[row] = logit_y[row] - log(sum over NPART partials)
// ---------------------------------------------------------------------------
__global__ __launch_bounds__(256) void finalize_kernel(const float* __restrict__ partial,
                                                       const float* __restrict__ logit_y,
                                                       float* __restrict__ out) {
    __shared__ float s[16][17];
    const int tid = threadIdx.x;
    const int jp = tid >> 4, r = tid & 15;
    const int rowbase = blockIdx.x * 16;

    float acc = 0.f;
    for (int j = jp; j < NPART; j += 16)
        acc += partial[(size_t)j * M_TOTAL + rowbase + r];
    s[jp][r] = acc;
    __syncthreads();

    if (tid < 16) {
        float t = 0.f;
        #pragma unroll
        for (int k = 0; k < 16; ++k) t += s[k][tid];
        out[rowbase + tid] = logit_y[rowbase + tid] - logf(t);
    }
}

// ---------------------------------------------------------------------------
extern "C" void kernel_launch(void* const* d_in, const int* in_sizes, int n_in,
                              void* d_out, int out_size, void* d_ws, size_t ws_size,
                              hipStream_t stream) {
    const float* latent  = (const float*)d_in[0];
    const float* vocab_w = (const float*)d_in[1];
    const float* vocab_b = (const float*)d_in[2];
    const int*   zi      = (const int*)d_in[3];
    const int*   y       = (const int*)d_in[4];
    float* out = (float*)d_out;

    char* ws = (char*)d_ws;
    float*         logit_y = (float*)(ws);                         // 16 KB
    float*         partial = (float*)(ws + 16384);                 // 1000*4096*4 = 16 MB
    unsigned char* zsb8    = (unsigned char*)(ws + 16384 + 16777216);            // 1 MB
    unsigned char* wt8     = (unsigned char*)(ws + 16384 + 16777216 + 1048576);  // 8 MB

    hipLaunchKernelGGL(traj_transpose_kernel, dim3(BATCH + 4 * (V / 64)), dim3(512), 0, stream,
                       latent, zi, vocab_w, zsb8, wt8);
    hipLaunchKernelGGL(gemm_lse_kernel, dim3(32 * NBN), dim3(512), 0, stream,
                       zsb8, wt8, vocab_b, y, partial, logit_y);
    hipLaunchKernelGGL(finalize_kernel, dim3(M_TOTAL / 16), dim3(256), 0, stream,
                       partial, logit_y, out);
}

// Round 9
// 160.369 us; speedup vs baseline: 2.3748x; 1.2263x over previous
//
#include <hip/hip_runtime.h>
#include <hip/hip_bf16.h>

#define BATCH 32
#define E 256
#define V 32000
#define NSTEP 128
#define M_TOTAL (BATCH * NSTEP)   // 4096
#define BM 128
#define BN2 64
#define NBT (V / BN2)             // 500 b-tiles
#define NGRP 16                   // bn groups per bm
#define NPART (2 * NGRP)          // 32 partial stripes

typedef __attribute__((ext_vector_type(4))) float f32x4;
typedef __attribute__((ext_vector_type(2))) float f32x2;
typedef __attribute__((ext_vector_type(8))) short s16x8;
typedef __attribute__((ext_vector_type(4))) unsigned int u32x4;

static __device__ __forceinline__ short f2bf(float v) {
    __hip_bfloat16 h = __float2bfloat16(v);
    return *reinterpret_cast<short*>(&h);
}

// fp8 e4m3 (OCP) conversions via HW packed-convert instructions.
static __device__ __forceinline__ unsigned char f2fp8(float v) {
    int p = __builtin_amdgcn_cvt_pk_fp8_f32(v, v, 0, false);
    return (unsigned char)(p & 0xff);
}
template<bool HI>
static __device__ __forceinline__ f32x2 fp8x2_to_f32(unsigned int x) {
    return __builtin_amdgcn_cvt_pk_f32_fp8((int)x, HI);
}

static __device__ __forceinline__ void gload_lds16(const void* g, void* l) {
    __builtin_amdgcn_global_load_lds((const __attribute__((address_space(1))) void*)g,
                                     (__attribute__((address_space(3))) void*)l,
                                     16, 0, 0);
}

// DPP row_ror reduction within each 16-lane row (VALU pipe, no LDS traffic).
template<int CTRL>
static __device__ __forceinline__ float dpp_add(float v) {
    int i = __builtin_amdgcn_update_dpp(0, __builtin_bit_cast(int, v), CTRL, 0xF, 0xF, false);
    return v + __builtin_bit_cast(float, i);
}
static __device__ __forceinline__ float row16_sum(float v) {
    v = dpp_add<0x121>(v);
    v = dpp_add<0x122>(v);
    v = dpp_add<0x124>(v);
    v = dpp_add<0x128>(v);
    return v;
}

// ---------------------------------------------------------------------------
// Kernel 1 (merged): blocks 0..31 = RNN trajectory (bf16 MFMA, trans-in-regs,
// fp32 scale recursion); blocks 32.. = vocab_w transpose+convert to fp8.
// ---------------------------------------------------------------------------
__global__ __launch_bounds__(512, 2) void traj_transpose_kernel(
        const float* __restrict__ latent, const int* __restrict__ zi,
        const float* __restrict__ w,
        unsigned char* __restrict__ zsb8, unsigned char* __restrict__ wt8) {
    __shared__ float tile[64][65];           // transpose path
    __shared__ __align__(16) short zsh[E];   // traj: z as bf16 (A-frag layout)
    __shared__ __align__(16) float red[16];  // traj: per-wave s / s2 partials

    const int tid = threadIdx.x;

    if (blockIdx.x >= BATCH) {
        const int bb = blockIdx.x - BATCH;   // 0..1999
        const int k0 = (bb & 3) * 64;
        const int n0 = (bb >> 2) * 64;
        const int c  = tid & 63;
        const int r8 = tid >> 6;
        #pragma unroll
        for (int r = r8; r < 64; r += 8)
            tile[r][c] = w[(size_t)(k0 + r) * V + n0 + c];
        __syncthreads();
        #pragma unroll
        for (int r = r8; r < 64; r += 8)
            wt8[(size_t)(n0 + r) * E + k0 + c] = f2fp8(tile[c][r]);
        return;
    }

    // ---- trajectory path: one batch per block, 8 waves ----
    const int b    = blockIdx.x;
    const int lane = tid & 63;
    const int wv   = tid >> 6;
    const int lm   = lane & 15;
    const int g    = lane >> 4;
    const float* tr = latent + (size_t)zi[b] * (E * E);

    s16x8 bfrag[2][8];
    #pragma unroll
    for (int nt = 0; nt < 2; ++nt)
        #pragma unroll
        for (int kk = 0; kk < 8; ++kk) {
            s16x8 fr;
            #pragma unroll
            for (int j = 0; j < 8; ++j)
                fr[j] = f2bf(tr[(size_t)(kk * 32 + g * 8 + j) * E + wv * 32 + nt * 16 + lm]);
            bfrag[nt][kk] = fr;
        }

    if (tid < E) zsh[tid] = f2bf(tr[tid]);

    {
        float v = (tid < E) ? tr[tid] : 0.f;
        float a = row16_sum(v), a2 = row16_sum(v * v);
        a  += __shfl_xor(a, 16);  a2 += __shfl_xor(a2, 16);
        a  += __shfl_xor(a, 32);  a2 += __shfl_xor(a2, 32);
        if (lane == 0) { red[wv] = a; red[8 + wv] = a2; }
    }
    __syncthreads();

    float scale;
    {
        f32x4 p0 = *(const f32x4*)&red[0], p1 = *(const f32x4*)&red[4];
        f32x4 q0 = *(const f32x4*)&red[8], q1 = *(const f32x4*)&red[12];
        float ts  = (p0[0]+p0[1]+p0[2]+p0[3]) + (p1[0]+p1[1]+p1[2]+p1[3]);
        float ts2 = (q0[0]+q0[1]+q0[2]+q0[3]) + (q1[0]+q1[1]+q1[2]+q1[3]);
        float var = fmaxf((ts2 - ts * ts * (1.0f / 256.0f)) * (1.0f / 255.0f), 0.f);
        scale = 0.113f / (1e-5f + sqrtf(var));
    }
    __syncthreads();

    for (int t = 0; t < NSTEP; ++t) {
        s16x8 a[8];
        #pragma unroll
        for (int kk = 0; kk < 8; ++kk)
            a[kk] = *(const s16x8*)((const char*)zsh + kk * 64 + g * 16);

        f32x4 acc0 = {}, acc1 = {};
        #pragma unroll
        for (int kk = 0; kk < 8; ++kk) {
            acc0 = __builtin_amdgcn_mfma_f32_16x16x32_bf16(a[kk], bfrag[0][kk], acc0, 0, 0, 0);
            acc1 = __builtin_amdgcn_mfma_f32_16x16x32_bf16(a[kk], bfrag[1][kk], acc1, 0, 0, 0);
        }

        float u  = row16_sum(acc0[0] + acc1[0]);
        float u2 = row16_sum(acc0[0] * acc0[0] + acc1[0] * acc1[0]);
        if (lane == 0) { red[wv] = u; red[8 + wv] = u2; }
        __syncthreads();

        f32x4 p0 = *(const f32x4*)&red[0], p1 = *(const f32x4*)&red[4];
        f32x4 q0 = *(const f32x4*)&red[8], q1 = *(const f32x4*)&red[12];
        float ts  = (p0[0]+p0[1]+p0[2]+p0[3]) + (p1[0]+p1[1]+p1[2]+p1[3]);
        float ts2 = (q0[0]+q0[1]+q0[2]+q0[3]) + (q1[0]+q1[1]+q1[2]+q1[3]);
        float var = fmaxf((ts2 - ts * ts * (1.0f / 256.0f)) * (1.0f / 255.0f), 0.f);
        float stdr = sqrtf(var);

        float e0 = scale * acc0[0], e1 = scale * acc1[0];
        if (g == 0) {
            zsh[wv * 32 + lm]      = f2bf(e0);
            zsh[wv * 32 + 16 + lm] = f2bf(e1);
            unsigned char* zr = zsb8 + ((size_t)b * NSTEP + t) * E + wv * 32;
            zr[lm]      = f2fp8(e0);
            zr[16 + lm] = f2fp8(e1);
        }
        scale = 0.113f / (1e-5f + scale * stdr);
        __syncthreads();
    }
}

// ---------------------------------------------------------------------------
// Kernel 2: persistent-panel fp8 GEMM + register-accumulated LSE partials.
// 512 blocks (2/CU), 256 threads (4 waves of 64x32 output). Block owns bm:
// A tile (128x256 fp8, 32 KB) staged once; loops ~31 BN=64 B-tiles with
// double-buffered B (2x16 KB). 2-phase pipeline: stage B[i+1] -> compute
// tile i -> barrier. exp-rowsum accumulates in registers across the loop.
// ---------------------------------------------------------------------------
__global__ __launch_bounds__(256, 2) void gemm_lse_kernel(const unsigned char* __restrict__ zsb8,
                                                          const unsigned char* __restrict__ wt8,
                                                          const float* __restrict__ vb,
                                                          float* __restrict__ partial) {
    __shared__ unsigned char apan[BM * E];        // 32 KB
    __shared__ unsigned char bpan[2][BN2 * E];    // 2 x 16 KB

    const int tid  = threadIdx.x;
    const int lane = tid & 63;
    const int w    = tid >> 6;         // 0..3
    const int bm   = blockIdx.x >> 4;  // 0..31
    const int grp  = blockIdx.x & 15;  // 0..15
    const int m0   = bm * BM;
    const int t0   = (NBT * grp) >> 4;
    const int t1   = (NBT * (grp + 1)) >> 4;

    // ---- stage A once: rotate layout LDS[row][slot] = G[row][(slot-row)&15] ----
    #pragma unroll
    for (int i = 0; i < 8; ++i) {
        const int c   = i * 256 + tid;          // 16B chunk id, 0..2047
        const int row = c >> 4;
        const int gsl = ((c & 15) - row) & 15;
        gload_lds16(zsb8 + (size_t)(m0 + row) * E + gsl * 16, (char*)apan + c * 16);
    }
    // ---- stage first B tile into buf 0 ----
    {
        const int n0 = t0 * BN2;
        #pragma unroll
        for (int i = 0; i < 4; ++i) {
            const int c   = i * 256 + tid;      // 0..1023
            const int row = c >> 4;
            const int gsl = ((c & 15) - row) & 15;
            gload_lds16(wt8 + (size_t)(n0 + row) * E + gsl * 16, (char*)bpan[0] + c * 16);
        }
    }

    const int wr = w >> 1, wc = w & 1;
    const int lm = lane & 15, lk = lane >> 4;
    const int h  = (lk & 1) * 8;

    float rs[4][4] = {};   // [rt][r] exp-sum accumulated over all tiles

    __syncthreads();       // A + B[0] resident

    for (int i = t0; i < t1; ++i) {
        const int cur = (i - t0) & 1;
        // ---- issue next tile's stage first (hides under compute) ----
        if (i + 1 < t1) {
            const int n0n = (i + 1) * BN2;
            #pragma unroll
            for (int j = 0; j < 4; ++j) {
                const int c   = j * 256 + tid;
                const int row = c >> 4;
                const int gsl = ((c & 15) - row) & 15;
                gload_lds16(wt8 + (size_t)(n0n + row) * E + gsl * 16,
                            (char*)bpan[cur ^ 1] + c * 16);
            }
        }

        const int n0 = i * BN2;
        const float bias0 = vb[n0 + wc * 32 + lm];
        const float bias1 = vb[n0 + wc * 32 + 16 + lm];

        f32x4 acc[4][2] = {};
        const unsigned char* bp = bpan[cur];
        #pragma unroll
        for (int kk = 0; kk < 8; ++kk) {
            const int c0 = kk * 2 + (lk >> 1);
            long long bfr[2];
            #pragma unroll
            for (int nt = 0; nt < 2; ++nt) {
                const int rn = wc * 32 + nt * 16 + lm;
                bfr[nt] = *(const long long*)(bp + rn * 256 + ((c0 + rn) & 15) * 16 + h);
            }
            #pragma unroll
            for (int rt = 0; rt < 4; ++rt) {
                const int ra = wr * 64 + rt * 16 + lm;
                const long long af = *(const long long*)(apan + ra * 256 + ((c0 + ra) & 15) * 16 + h);
                acc[rt][0] = __builtin_amdgcn_mfma_f32_16x16x32_fp8_fp8(af, bfr[0], acc[rt][0], 0, 0, 0);
                acc[rt][1] = __builtin_amdgcn_mfma_f32_16x16x32_fp8_fp8(af, bfr[1], acc[rt][1], 0, 0, 0);
            }
        }

        // ---- epilogue: accumulate exp into registers (no stores) ----
        #pragma unroll
        for (int rt = 0; rt < 4; ++rt)
            #pragma unroll
            for (int r = 0; r < 4; ++r)
                rs[rt][r] += __expf(acc[rt][0][r] + bias0) + __expf(acc[rt][1][r] + bias1);

        __syncthreads();   // drains stage of B[i+1]; all reads of bpan[cur] done
    }

    // ---- one reduce + store per block ----
    const int cr = lane >> 4;
    #pragma unroll
    for (int rt = 0; rt < 4; ++rt)
        #pragma unroll
        for (int r = 0; r < 4; ++r) {
            const float v = row16_sum(rs[rt][r]);
            if (lm == 0)
                partial[(size_t)(grp * 2 + wc) * M_TOTAL + m0 + wr * 64 + rt * 16 + cr * 4 + r] = v;
        }
}

// ---------------------------------------------------------------------------
// Kernel 3: finalize. Per row: target logit via tiny fp8 dot (same quantized
// data as the gemm) + log of the 32-stripe partial sum.
// ---------------------------------------------------------------------------
__global__ __launch_bounds__(256) void finalize_kernel(const unsigned char* __restrict__ zsb8,
                                                       const unsigned char* __restrict__ wt8,
                                                       const float* __restrict__ vb,
                                                       const int* __restrict__ y,
                                                       const float* __restrict__ partial,
                                                       float* __restrict__ out) {
    const int tid  = threadIdx.x;
    const int lane = tid & 63;
    const int rw   = lane >> 4;        // row within wave (0..3)
    const int kl   = lane & 15;        // k-slice / stripe lane
    const int row  = blockIdx.x * 16 + (tid >> 6) * 4 + rw;
    const int yrow = y[row];

    // target logit: dot of 256 fp8 pairs, 16 bytes per lane
    u32x4 za = *(const u32x4*)(zsb8 + (size_t)row * E + kl * 16);
    u32x4 wa = *(const u32x4*)(wt8 + (size_t)yrow * E + kl * 16);
    float acc = 0.f;
    #pragma unroll
    for (int q = 0; q < 4; ++q) {
        f32x2 a0 = fp8x2_to_f32<false>(za[q]), b0 = fp8x2_to_f32<false>(wa[q]);
        f32x2 a1 = fp8x2_to_f32<true>(za[q]),  b1 = fp8x2_to_f32<true>(wa[q]);
        acc += a0[0] * b0[0] + a0[1] * b0[1] + a1[0] * b1[0] + a1[1] * b1[1];
    }
    const float logit = row16_sum(acc) + vb[yrow];

    // rowsum over 32 stripes (2 per lane)
    float ps = partial[(size_t)kl * M_TOTAL + row] + partial[(size_t)(kl + 16) * M_TOTAL + row];
    const float tot = row16_sum(ps);

    if (kl == 0) out[row] = logit - logf(tot);
}

// ---------------------------------------------------------------------------
extern "C" void kernel_launch(void* const* d_in, const int* in_sizes, int n_in,
                              void* d_out, int out_size, void* d_ws, size_t ws_size,
                              hipStream_t stream) {
    const float* latent  = (const float*)d_in[0];
    const float* vocab_w = (const float*)d_in[1];
    const float* vocab_b = (const float*)d_in[2];
    const int*   zi      = (const int*)d_in[3];
    const int*   y       = (const int*)d_in[4];
    float* out = (float*)d_out;

    char* ws = (char*)d_ws;
    float*         partial = (float*)(ws);                             // 32*4096*4 = 512 KB
    unsigned char* zsb8    = (unsigned char*)(ws + 524288);            // 1 MB
    unsigned char* wt8     = (unsigned char*)(ws + 524288 + 1048576);  // 8 MB

    hipLaunchKernelGGL(traj_transpose_kernel, dim3(BATCH + 4 * (V / 64)), dim3(512), 0, stream,
                       latent, zi, vocab_w, zsb8, wt8);
    hipLaunchKernelGGL(gemm_lse_kernel, dim3(32 * NGRP), dim3(256), 0, stream,
                       zsb8, wt8, vocab_b, partial);
    hipLaunchKernelGGL(finalize_kernel, dim3(M_TOTAL / 16), dim3(256), 0, stream,
                       zsb8, wt8, vocab_b, y, partial, out);
}

// Round 10
// 152.815 us; speedup vs baseline: 2.4922x; 1.0494x over previous
//
#include <hip/hip_runtime.h>
#include <hip/hip_bf16.h>

#define BATCH 32
#define E 256
#define V 32000
#define NSTEP 128
#define M_TOTAL (BATCH * NSTEP)   // 4096
#define BM 128
#define BN2 128
#define NBT (V / BN2)             // 250 b-tiles
#define NGRP 16                   // bn groups
#define NPART (2 * NGRP)          // 32 partial stripes

typedef __attribute__((ext_vector_type(4))) float f32x4;
typedef __attribute__((ext_vector_type(2))) float f32x2;
typedef __attribute__((ext_vector_type(8))) short s16x8;
typedef __attribute__((ext_vector_type(4))) unsigned int u32x4;

static __device__ __forceinline__ short f2bf(float v) {
    __hip_bfloat16 h = __float2bfloat16(v);
    return *reinterpret_cast<short*>(&h);
}

// fp8 e4m3 (OCP) conversions via HW packed-convert instructions.
static __device__ __forceinline__ unsigned char f2fp8(float v) {
    int p = __builtin_amdgcn_cvt_pk_fp8_f32(v, v, 0, false);
    return (unsigned char)(p & 0xff);
}
template<bool HI>
static __device__ __forceinline__ f32x2 fp8x2_to_f32(unsigned int x) {
    return __builtin_amdgcn_cvt_pk_f32_fp8((int)x, HI);
}

// frag-major byte position within a 256-B row: element e -> lk*64 + kk*8 + j
// (e = kk*32 + lk*8 + j). Lane lk's (kk,kk+1) fragments are 16-B contiguous.
static __device__ __forceinline__ int fragpos(int e) {
    return ((e >> 3) & 3) * 64 + (e >> 5) * 8 + (e & 7);
}

static __device__ __forceinline__ long long ll2(unsigned int a, unsigned int b) {
    return (long long)(((unsigned long long)b << 32) | a);
}

static __device__ __forceinline__ void gload_lds16(const void* g, void* l) {
    __builtin_amdgcn_global_load_lds((const __attribute__((address_space(1))) void*)g,
                                     (__attribute__((address_space(3))) void*)l,
                                     16, 0, 0);
}

// DPP row_ror reduction within each 16-lane row (VALU pipe, no LDS traffic).
template<int CTRL>
static __device__ __forceinline__ float dpp_add(float v) {
    int i = __builtin_amdgcn_update_dpp(0, __builtin_bit_cast(int, v), CTRL, 0xF, 0xF, false);
    return v + __builtin_bit_cast(float, i);
}
static __device__ __forceinline__ float row16_sum(float v) {
    v = dpp_add<0x121>(v);
    v = dpp_add<0x122>(v);
    v = dpp_add<0x124>(v);
    v = dpp_add<0x128>(v);
    return v;
}

// ---------------------------------------------------------------------------
// Kernel 1 (merged): blocks 0..31 = RNN trajectory (bf16 MFMA, trans-in-regs,
// one barrier per step, fp32 scale recursion); blocks 32.. = vocab_w
// transpose+convert to frag-major fp8.
// ---------------------------------------------------------------------------
__global__ __launch_bounds__(512, 2) void traj_transpose_kernel(
        const float* __restrict__ latent, const int* __restrict__ zi,
        const float* __restrict__ w,
        unsigned char* __restrict__ zsb8, unsigned char* __restrict__ wt8) {
    __shared__ float tile[64][65];              // transpose path
    __shared__ __align__(16) short zsh[2][E];   // traj: z bf16, double-buffered
    __shared__ __align__(16) float red[2][16];  // traj: per-wave partials, dbuf

    const int tid = threadIdx.x;

    if (blockIdx.x >= BATCH) {
        const int bb = blockIdx.x - BATCH;   // 0..1999
        const int k0 = (bb & 3) * 64;
        const int n0 = (bb >> 2) * 64;
        const int c  = tid & 63;
        const int r8 = tid >> 6;
        #pragma unroll
        for (int r = r8; r < 64; r += 8)
            tile[r][c] = w[(size_t)(k0 + r) * V + n0 + c];
        __syncthreads();
        const int fp = fragpos(k0 + c);
        #pragma unroll
        for (int r = r8; r < 64; r += 8)
            wt8[(size_t)(n0 + r) * E + fp] = f2fp8(tile[c][r]);
        return;
    }

    // ---- trajectory path: one batch per block, 8 waves ----
    const int b    = blockIdx.x;
    const int lane = tid & 63;
    const int wv   = tid >> 6;
    const int lm   = lane & 15;
    const int g    = lane >> 4;
    const float* tr = latent + (size_t)zi[b] * (E * E);

    s16x8 bfrag[2][8];
    #pragma unroll
    for (int nt = 0; nt < 2; ++nt)
        #pragma unroll
        for (int kk = 0; kk < 8; ++kk) {
            s16x8 fr;
            #pragma unroll
            for (int j = 0; j < 8; ++j)
                fr[j] = f2bf(tr[(size_t)(kk * 32 + g * 8 + j) * E + wv * 32 + nt * 16 + lm]);
            bfrag[nt][kk] = fr;
        }

    if (tid < E) zsh[0][tid] = f2bf(tr[tid]);

    {   // scale_0 from std(z0); pre-loop reduction uses red[1]
        float v = (tid < E) ? tr[tid] : 0.f;
        float a = row16_sum(v), a2 = row16_sum(v * v);
        a  += __shfl_xor(a, 16);  a2 += __shfl_xor(a2, 16);
        a  += __shfl_xor(a, 32);  a2 += __shfl_xor(a2, 32);
        if (lane == 0) { red[1][wv] = a; red[1][8 + wv] = a2; }
    }
    __syncthreads();

    float scale;
    {
        f32x4 p0 = *(const f32x4*)&red[1][0], p1 = *(const f32x4*)&red[1][4];
        f32x4 q0 = *(const f32x4*)&red[1][8], q1 = *(const f32x4*)&red[1][12];
        float ts  = (p0[0]+p0[1]+p0[2]+p0[3]) + (p1[0]+p1[1]+p1[2]+p1[3]);
        float ts2 = (q0[0]+q0[1]+q0[2]+q0[3]) + (q1[0]+q1[1]+q1[2]+q1[3]);
        float var = fmaxf((ts2 - ts * ts * (1.0f / 256.0f)) * (1.0f / 255.0f), 0.f);
        scale = 0.113f / (1e-5f + sqrtf(var));
    }

    const int p0i = fragpos(wv * 32 + lm);        // frag-major positions
    const int p1i = fragpos(wv * 32 + 16 + lm);

    for (int t = 0; t < NSTEP; ++t) {
        const short* zrd = zsh[t & 1];
        s16x8 a[8];
        #pragma unroll
        for (int kk = 0; kk < 8; ++kk)
            a[kk] = *(const s16x8*)((const char*)zrd + kk * 64 + g * 16);

        f32x4 acc0 = {}, acc1 = {};
        #pragma unroll
        for (int kk = 0; kk < 8; ++kk) {
            acc0 = __builtin_amdgcn_mfma_f32_16x16x32_bf16(a[kk], bfrag[0][kk], acc0, 0, 0, 0);
            acc1 = __builtin_amdgcn_mfma_f32_16x16x32_bf16(a[kk], bfrag[1][kk], acc1, 0, 0, 0);
        }

        // scale_t known at step start -> scaled write needs no extra barrier
        const float e0 = scale * acc0[0], e1 = scale * acc1[0];
        if (g == 0) {
            zsh[(t + 1) & 1][wv * 32 + lm]      = f2bf(e0);
            zsh[(t + 1) & 1][wv * 32 + 16 + lm] = f2bf(e1);
            unsigned char* zr = zsb8 + ((size_t)b * NSTEP + t) * E;
            zr[p0i] = f2fp8(e0);
            zr[p1i] = f2fp8(e1);
        }

        // reduce RAW stats (for next step's scale), carried one step ahead
        float u  = row16_sum(acc0[0] + acc1[0]);
        float u2 = row16_sum(acc0[0] * acc0[0] + acc1[0] * acc1[0]);
        if (lane == 0) { red[t & 1][wv] = u; red[t & 1][8 + wv] = u2; }
        __syncthreads();

        const float* rd = red[t & 1];
        f32x4 r0 = *(const f32x4*)&rd[0], r1 = *(const f32x4*)&rd[4];
        f32x4 s0 = *(const f32x4*)&rd[8], s1 = *(const f32x4*)&rd[12];
        float ts  = (r0[0]+r0[1]+r0[2]+r0[3]) + (r1[0]+r1[1]+r1[2]+r1[3]);
        float ts2 = (s0[0]+s0[1]+s0[2]+s0[3]) + (s1[0]+s1[1]+s1[2]+s1[3]);
        float var = fmaxf((ts2 - ts * ts * (1.0f / 256.0f)) * (1.0f / 255.0f), 0.f);
        scale = 0.113f / (1e-5f + scale * sqrtf(var));
    }
}

// ---------------------------------------------------------------------------
// Kernel 2: persistent fp8 GEMM + register-accumulated LSE partials.
// 512 blocks (2/CU), 256 threads (4 waves, wave tile 64x64, acc 64 VGPR).
// A-fragments (64 rows x K=256 fp8) read ONCE from global into 64 VGPR
// (256-VGPR cap at 2 waves/SIMD -> no spill). B tiles 128x256 fp8 in LDS,
// double-buffered (2x32 KB), frag-major + rotate-slot layout ->
// 16 ds_read_b128 per tile per wave. 2-phase pipeline, one barrier per tile.
// ---------------------------------------------------------------------------
__global__ __launch_bounds__(256, 2) void gemm_lse_kernel(const unsigned char* __restrict__ zsb8,
                                                          const unsigned char* __restrict__ wt8,
                                                          const float* __restrict__ vb,
                                                          float* __restrict__ partial) {
    __shared__ unsigned char bpan[2][BN2 * E];    // 2 x 32 KB

    const int tid  = threadIdx.x;
    const int lane = tid & 63;
    const int w    = tid >> 6;         // 0..3
    const int bm   = blockIdx.x >> 4;  // 0..31
    const int grp  = blockIdx.x & 15;  // 0..15 (bid%8 = grp%8 -> grp-mates share XCD)
    const int m0   = bm * BM;
    const int t0   = (NBT * grp) >> 4;
    const int t1   = (NBT * (grp + 1)) >> 4;

    const int wr = w >> 1, wc = w & 1;
    const int lm = lane & 15, lk = lane >> 4;
    const int mw = m0 + wr * 64;

    // ---- A-fragments once from global (frag-major rows: 16B = kk pair) ----
    long long areg[4][8];
    #pragma unroll
    for (int rt = 0; rt < 4; ++rt)
        #pragma unroll
        for (int kp = 0; kp < 4; ++kp) {
            u32x4 v = *(const u32x4*)(zsb8 + (size_t)(mw + rt * 16 + lm) * E + lk * 64 + kp * 16);
            areg[rt][2 * kp]     = ll2(v[0], v[1]);
            areg[rt][2 * kp + 1] = ll2(v[2], v[3]);
        }

    // ---- stage first B tile ----
    {
        const size_t gbase = (size_t)(t0 * BN2) * E;
        #pragma unroll
        for (int i = 0; i < 8; ++i) {
            const int c   = i * 256 + tid;          // 16B chunk 0..2047
            const int row = c >> 4;
            const int gsl = ((c & 15) - row) & 15;
            gload_lds16(wt8 + gbase + (size_t)row * E + gsl * 16, (char*)bpan[0] + c * 16);
        }
    }

    float rs[4][4] = {};   // [rt][r] exp-sum accumulated over all tiles

    __syncthreads();       // B[0] resident (drains vmcnt)

    for (int i = t0; i < t1; ++i) {
        const int cur = (i - t0) & 1;
        if (i + 1 < t1) {   // issue next stage first; hides under compute
            const size_t gbase = (size_t)((i + 1) * BN2) * E;
            #pragma unroll
            for (int j = 0; j < 8; ++j) {
                const int c   = j * 256 + tid;
                const int row = c >> 4;
                const int gsl = ((c & 15) - row) & 15;
                gload_lds16(wt8 + gbase + (size_t)row * E + gsl * 16,
                            (char*)bpan[cur ^ 1] + c * 16);
            }
        }

        const int n0 = i * BN2;
        float bias[4];
        #pragma unroll
        for (int nt = 0; nt < 4; ++nt) bias[nt] = vb[n0 + wc * 64 + nt * 16 + lm];

        f32x4 acc[4][4] = {};
        const unsigned char* bp = bpan[cur];
        #pragma unroll
        for (int kp = 0; kp < 4; ++kp) {
            long long blo[4], bhi[4];
            #pragma unroll
            for (int nt = 0; nt < 4; ++nt) {
                const int rn   = wc * 64 + nt * 16 + lm;
                const int slot = (lk * 4 + kp + rn) & 15;
                u32x4 bv = *(const u32x4*)(bp + rn * 256 + slot * 16);
                blo[nt] = ll2(bv[0], bv[1]);
                bhi[nt] = ll2(bv[2], bv[3]);
            }
            #pragma unroll
            for (int rt = 0; rt < 4; ++rt)
                #pragma unroll
                for (int nt = 0; nt < 4; ++nt)
                    acc[rt][nt] = __builtin_amdgcn_mfma_f32_16x16x32_fp8_fp8(
                        areg[rt][2 * kp], blo[nt], acc[rt][nt], 0, 0, 0);
            #pragma unroll
            for (int rt = 0; rt < 4; ++rt)
                #pragma unroll
                for (int nt = 0; nt < 4; ++nt)
                    acc[rt][nt] = __builtin_amdgcn_mfma_f32_16x16x32_fp8_fp8(
                        areg[rt][2 * kp + 1], bhi[nt], acc[rt][nt], 0, 0, 0);
        }

        // ---- accumulate exp into registers (no stores) ----
        #pragma unroll
        for (int rt = 0; rt < 4; ++rt)
            #pragma unroll
            for (int nt = 0; nt < 4; ++nt)
                #pragma unroll
                for (int r = 0; r < 4; ++r)
                    rs[rt][r] += __expf(acc[rt][nt][r] + bias[nt]);

        __syncthreads();   // drains next-stage vmcnt; bpan[cur] reads done
    }

    // ---- one reduce + store per block ----
    const int cr = lane >> 4;
    #pragma unroll
    for (int rt = 0; rt < 4; ++rt)
        #pragma unroll
        for (int r = 0; r < 4; ++r) {
            const float v = row16_sum(rs[rt][r]);
            if (lm == 0)
                partial[(size_t)(grp * 2 + wc) * M_TOTAL + mw + rt * 16 + cr * 4 + r] = v;
        }
}

// ---------------------------------------------------------------------------
// Kernel 3: finalize. Target logit via tiny fp8 dot (frag-major rows: the
// shared permutation cancels in the dot) + log of the 32-stripe partial sum.
// ---------------------------------------------------------------------------
__global__ __launch_bounds__(256) void finalize_kernel(const unsigned char* __restrict__ zsb8,
                                                       const unsigned char* __restrict__ wt8,
                                                       const float* __restrict__ vb,
                                                       const int* __restrict__ y,
                                                       const float* __restrict__ partial,
                                                       float* __restrict__ out) {
    const int tid  = threadIdx.x;
    const int lane = tid & 63;
    const int rw   = lane >> 4;
    const int kl   = lane & 15;
    const int row  = blockIdx.x * 16 + (tid >> 6) * 4 + rw;
    const int yrow = y[row];

    u32x4 za = *(const u32x4*)(zsb8 + (size_t)row * E + kl * 16);
    u32x4 wa = *(const u32x4*)(wt8 + (size_t)yrow * E + kl * 16);
    float acc = 0.f;
    #pragma unroll
    for (int q = 0; q < 4; ++q) {
        f32x2 a0 = fp8x2_to_f32<false>(za[q]), b0 = fp8x2_to_f32<false>(wa[q]);
        f32x2 a1 = fp8x2_to_f32<true>(za[q]),  b1 = fp8x2_to_f32<true>(wa[q]);
        acc += a0[0] * b0[0] + a0[1] * b0[1] + a1[0] * b1[0] + a1[1] * b1[1];
    }
    const float logit = row16_sum(acc) + vb[yrow];

    float ps = partial[(size_t)kl * M_TOTAL + row] + partial[(size_t)(kl + 16) * M_TOTAL + row];
    const float tot = row16_sum(ps);

    if (kl == 0) out[row] = logit - logf(tot);
}

// ---------------------------------------------------------------------------
extern "C" void kernel_launch(void* const* d_in, const int* in_sizes, int n_in,
                              void* d_out, int out_size, void* d_ws, size_t ws_size,
                              hipStream_t stream) {
    const float* latent  = (const float*)d_in[0];
    const float* vocab_w = (const float*)d_in[1];
    const float* vocab_b = (const float*)d_in[2];
    const int*   zi      = (const int*)d_in[3];
    const int*   y       = (const int*)d_in[4];
    float* out = (float*)d_out;

    char* ws = (char*)d_ws;
    float*         partial = (float*)(ws);                             // 512 KB
    unsigned char* zsb8    = (unsigned char*)(ws + 524288);            // 1 MB
    unsigned char* wt8     = (unsigned char*)(ws + 524288 + 1048576);  // 8 MB

    hipLaunchKernelGGL(traj_transpose_kernel, dim3(BATCH + 4 * (V / 64)), dim3(512), 0, stream,
                       latent, zi, vocab_w, zsb8, wt8);
    hipLaunchKernelGGL(gemm_lse_kernel, dim3(32 * NGRP), dim3(256), 0, stream,
                       zsb8, wt8, vocab_b, partial);
    hipLaunchKernelGGL(finalize_kernel, dim3(M_TOTAL / 16), dim3(256), 0, stream,
                       zsb8, wt8, vocab_b, y, partial, out);
}

// Round 11
// 151.894 us; speedup vs baseline: 2.5073x; 1.0061x over previous
//
#include <hip/hip_runtime.h>
#include <hip/hip_bf16.h>

#define BATCH 32
#define E 256
#define V 32000
#define NSTEP 128
#define M_TOTAL (BATCH * NSTEP)   // 4096
#define BM 128
#define BN2 128
#define NBT (V / BN2)             // 250 b-tiles
#define NGRP 8                    // bn groups (== XCDs)
#define L2E 1.4426950408889634f

typedef __attribute__((ext_vector_type(4))) float f32x4;
typedef __attribute__((ext_vector_type(2))) float f32x2;
typedef __attribute__((ext_vector_type(8))) short s16x8;
typedef __attribute__((ext_vector_type(4))) unsigned int u32x4;

static __device__ __forceinline__ short f2bf(float v) {
    __hip_bfloat16 h = __float2bfloat16(v);
    return *reinterpret_cast<short*>(&h);
}

// fp8 e4m3 (OCP) conversions via HW packed-convert instructions.
static __device__ __forceinline__ unsigned char f2fp8(float v) {
    int p = __builtin_amdgcn_cvt_pk_fp8_f32(v, v, 0, false);
    return (unsigned char)(p & 0xff);
}
template<bool HI>
static __device__ __forceinline__ f32x2 fp8x2_to_f32(unsigned int x) {
    return __builtin_amdgcn_cvt_pk_f32_fp8((int)x, HI);
}

// frag-major byte position within a 256-B row: element e -> lk*64 + kk*8 + j
static __device__ __forceinline__ int fragpos(int e) {
    return ((e >> 3) & 3) * 64 + (e >> 5) * 8 + (e & 7);
}

static __device__ __forceinline__ long long ll2(unsigned int a, unsigned int b) {
    return (long long)(((unsigned long long)b << 32) | a);
}

static __device__ __forceinline__ void gload_lds16(const void* g, void* l) {
    __builtin_amdgcn_global_load_lds((const __attribute__((address_space(1))) void*)g,
                                     (__attribute__((address_space(3))) void*)l,
                                     16, 0, 0);
}

// DPP row_ror reduction within each 16-lane row (VALU pipe, no LDS traffic).
template<int CTRL>
static __device__ __forceinline__ float dpp_add(float v) {
    int i = __builtin_amdgcn_update_dpp(0, __builtin_bit_cast(int, v), CTRL, 0xF, 0xF, false);
    return v + __builtin_bit_cast(float, i);
}
static __device__ __forceinline__ float row16_sum(float v) {
    v = dpp_add<0x121>(v);
    v = dpp_add<0x122>(v);
    v = dpp_add<0x124>(v);
    v = dpp_add<0x128>(v);
    return v;
}

// ---------------------------------------------------------------------------
// Kernel 1 (merged): blocks 0..31 = RNN trajectory (bf16 MFMA, trans-in-regs,
// one barrier per step); blocks 32.. = vocab_w transpose -> frag-major fp8.
// ---------------------------------------------------------------------------
__global__ __launch_bounds__(512, 2) void traj_transpose_kernel(
        const float* __restrict__ latent, const int* __restrict__ zi,
        const float* __restrict__ w,
        unsigned char* __restrict__ zsb8, unsigned char* __restrict__ wt8) {
    __shared__ float tile[64][65];              // transpose path
    __shared__ __align__(16) short zsh[2][E];   // traj: z bf16, double-buffered
    __shared__ __align__(16) float red[2][16];  // traj: per-wave partials, dbuf

    const int tid = threadIdx.x;

    if (blockIdx.x >= BATCH) {
        const int bb = blockIdx.x - BATCH;   // 0..1999
        const int k0 = (bb & 3) * 64;
        const int n0 = (bb >> 2) * 64;
        const int c  = tid & 63;
        const int r8 = tid >> 6;
        #pragma unroll
        for (int r = r8; r < 64; r += 8)
            tile[r][c] = w[(size_t)(k0 + r) * V + n0 + c];
        __syncthreads();
        const int fp = fragpos(k0 + c);
        #pragma unroll
        for (int r = r8; r < 64; r += 8)
            wt8[(size_t)(n0 + r) * E + fp] = f2fp8(tile[c][r]);
        return;
    }

    // ---- trajectory path: one batch per block, 8 waves ----
    const int b    = blockIdx.x;
    const int lane = tid & 63;
    const int wv   = tid >> 6;
    const int lm   = lane & 15;
    const int g    = lane >> 4;
    const float* tr = latent + (size_t)zi[b] * (E * E);

    s16x8 bfrag[2][8];
    #pragma unroll
    for (int nt = 0; nt < 2; ++nt)
        #pragma unroll
        for (int kk = 0; kk < 8; ++kk) {
            s16x8 fr;
            #pragma unroll
            for (int j = 0; j < 8; ++j)
                fr[j] = f2bf(tr[(size_t)(kk * 32 + g * 8 + j) * E + wv * 32 + nt * 16 + lm]);
            bfrag[nt][kk] = fr;
        }

    if (tid < E) zsh[0][tid] = f2bf(tr[tid]);

    {   // scale_0 from std(z0); pre-loop reduction uses red[1]
        float v = (tid < E) ? tr[tid] : 0.f;
        float a = row16_sum(v), a2 = row16_sum(v * v);
        a  += __shfl_xor(a, 16);  a2 += __shfl_xor(a2, 16);
        a  += __shfl_xor(a, 32);  a2 += __shfl_xor(a2, 32);
        if (lane == 0) { red[1][wv] = a; red[1][8 + wv] = a2; }
    }
    __syncthreads();

    float scale;
    {
        f32x4 p0 = *(const f32x4*)&red[1][0], p1 = *(const f32x4*)&red[1][4];
        f32x4 q0 = *(const f32x4*)&red[1][8], q1 = *(const f32x4*)&red[1][12];
        float ts  = (p0[0]+p0[1]+p0[2]+p0[3]) + (p1[0]+p1[1]+p1[2]+p1[3]);
        float ts2 = (q0[0]+q0[1]+q0[2]+q0[3]) + (q1[0]+q1[1]+q1[2]+q1[3]);
        float var = fmaxf((ts2 - ts * ts * (1.0f / 256.0f)) * (1.0f / 255.0f), 0.f);
        scale = 0.113f / (1e-5f + sqrtf(var));
    }

    const int p0i = fragpos(wv * 32 + lm);
    const int p1i = fragpos(wv * 32 + 16 + lm);

    for (int t = 0; t < NSTEP; ++t) {
        const short* zrd = zsh[t & 1];
        s16x8 a[8];
        #pragma unroll
        for (int kk = 0; kk < 8; ++kk)
            a[kk] = *(const s16x8*)((const char*)zrd + kk * 64 + g * 16);

        f32x4 acc0 = {}, acc1 = {};
        #pragma unroll
        for (int kk = 0; kk < 8; ++kk) {
            acc0 = __builtin_amdgcn_mfma_f32_16x16x32_bf16(a[kk], bfrag[0][kk], acc0, 0, 0, 0);
            acc1 = __builtin_amdgcn_mfma_f32_16x16x32_bf16(a[kk], bfrag[1][kk], acc1, 0, 0, 0);
        }

        const float e0 = scale * acc0[0], e1 = scale * acc1[0];
        if (g == 0) {
            zsh[(t + 1) & 1][wv * 32 + lm]      = f2bf(e0);
            zsh[(t + 1) & 1][wv * 32 + 16 + lm] = f2bf(e1);
            unsigned char* zr = zsb8 + ((size_t)b * NSTEP + t) * E;
            zr[p0i] = f2fp8(e0);
            zr[p1i] = f2fp8(e1);
        }

        float u  = row16_sum(acc0[0] + acc1[0]);
        float u2 = row16_sum(acc0[0] * acc0[0] + acc1[0] * acc1[0]);
        if (lane == 0) { red[t & 1][wv] = u; red[t & 1][8 + wv] = u2; }
        __syncthreads();

        const float* rd = red[t & 1];
        f32x4 r0 = *(const f32x4*)&rd[0], r1 = *(const f32x4*)&rd[4];
        f32x4 s0 = *(const f32x4*)&rd[8], s1 = *(const f32x4*)&rd[12];
        float ts  = (r0[0]+r0[1]+r0[2]+r0[3]) + (r1[0]+r1[1]+r1[2]+r1[3]);
        float ts2 = (s0[0]+s0[1]+s0[2]+s0[3]) + (s1[0]+s1[1]+s1[2]+s1[3]);
        float var = fmaxf((ts2 - ts * ts * (1.0f / 256.0f)) * (1.0f / 255.0f), 0.f);
        scale = 0.113f / (1e-5f + scale * sqrtf(var));
    }
}

// ---------------------------------------------------------------------------
// Kernel 2: persistent fp8 GEMM, 2-deep acc pipeline (epilogue of tile i-1
// overlaps MFMA of tile i on separate pipes). 256 blocks (1/CU), 512 threads
// (8 waves, wave tile 64x32). A (64 VGPR) register-resident; B 2x32 KB LDS
// double-buffer. exp2 with log2e folded into bias. One barrier per tile.
// ---------------------------------------------------------------------------
__global__ __launch_bounds__(512, 2) void gemm_lse_kernel(const unsigned char* __restrict__ zsb8,
                                                          const unsigned char* __restrict__ wt8,
                                                          const float* __restrict__ vb,
                                                          float* __restrict__ partial) {
    __shared__ unsigned char bpan0[BN2 * E];    // 32 KB
    __shared__ unsigned char bpan1[BN2 * E];    // 32 KB

    const int tid  = threadIdx.x;
    const int lane = tid & 63;
    const int w    = tid >> 6;         // 0..7
    const int grp  = blockIdx.x & 7;   // XCD id; grp-mates share B range in L2
    const int bm   = blockIdx.x >> 3;  // 0..31
    const int m0   = bm * BM;
    const int t0   = (NBT * grp) >> 3;
    const int t1   = (NBT * (grp + 1)) >> 3;

    const int wr = w >> 2, wc = w & 3;  // 2 x 4 wave grid, wave tile 64x32
    const int lm = lane & 15, lk = lane >> 4;
    const int mw = m0 + wr * 64;

    // ---- A-fragments once from global (frag-major rows: 16B = kk pair) ----
    long long areg[4][8];
    #pragma unroll
    for (int rt = 0; rt < 4; ++rt)
        #pragma unroll
        for (int kp = 0; kp < 4; ++kp) {
            u32x4 v = *(const u32x4*)(zsb8 + (size_t)(mw + rt * 16 + lm) * E + lk * 64 + kp * 16);
            areg[rt][2 * kp]     = ll2(v[0], v[1]);
            areg[rt][2 * kp + 1] = ll2(v[2], v[3]);
        }

    float rs[4][4] = {};   // [rt][r] exp-sum accumulated over all tiles

    auto STAGE = [&](int tile, unsigned char* dst) {
        const size_t gbase = (size_t)(tile * BN2) * E;
        #pragma unroll
        for (int j = 0; j < 4; ++j) {
            const int c   = j * 512 + tid;      // 16B chunk 0..2047
            const int row = c >> 4;
            const int gsl = ((c & 15) - row) & 15;
            gload_lds16(wt8 + gbase + (size_t)row * E + gsl * 16, dst + c * 16);
        }
    };

    auto COMPUTE = [&](const unsigned char* bp, f32x4 (&acc)[4][2], float (&bias)[2], int tile) {
        const int n0 = tile * BN2;
        bias[0] = vb[n0 + wc * 32 + lm] * L2E;
        bias[1] = vb[n0 + wc * 32 + 16 + lm] * L2E;
        #pragma unroll
        for (int rt = 0; rt < 4; ++rt) { acc[rt][0] = (f32x4){}; acc[rt][1] = (f32x4){}; }
        #pragma unroll
        for (int kp = 0; kp < 4; ++kp) {
            long long blo[2], bhi[2];
            #pragma unroll
            for (int nt = 0; nt < 2; ++nt) {
                const int rn   = wc * 32 + nt * 16 + lm;
                const int slot = (lk * 4 + kp + rn) & 15;
                u32x4 bv = *(const u32x4*)(bp + rn * 256 + slot * 16);
                blo[nt] = ll2(bv[0], bv[1]);
                bhi[nt] = ll2(bv[2], bv[3]);
            }
            #pragma unroll
            for (int rt = 0; rt < 4; ++rt) {
                acc[rt][0] = __builtin_amdgcn_mfma_f32_16x16x32_fp8_fp8(areg[rt][2 * kp], blo[0], acc[rt][0], 0, 0, 0);
                acc[rt][1] = __builtin_amdgcn_mfma_f32_16x16x32_fp8_fp8(areg[rt][2 * kp], blo[1], acc[rt][1], 0, 0, 0);
            }
            #pragma unroll
            for (int rt = 0; rt < 4; ++rt) {
                acc[rt][0] = __builtin_amdgcn_mfma_f32_16x16x32_fp8_fp8(areg[rt][2 * kp + 1], bhi[0], acc[rt][0], 0, 0, 0);
                acc[rt][1] = __builtin_amdgcn_mfma_f32_16x16x32_fp8_fp8(areg[rt][2 * kp + 1], bhi[1], acc[rt][1], 0, 0, 0);
            }
        }
    };

    auto EPI = [&](const f32x4 (&acc)[4][2], const float (&bias)[2]) {
        #pragma unroll
        for (int rt = 0; rt < 4; ++rt)
            #pragma unroll
            for (int r = 0; r < 4; ++r)
                rs[rt][r] += __builtin_amdgcn_exp2f(acc[rt][0][r] * L2E + bias[0])
                           + __builtin_amdgcn_exp2f(acc[rt][1][r] * L2E + bias[1]);
    };

    f32x4 accA[4][2], accB[4][2];
    float biasA[2], biasB[2];

    // ---- prologue: tile t0 into accA (no epilogue yet) ----
    STAGE(t0, bpan0);
    __syncthreads();
    if (t0 + 1 < t1) STAGE(t0 + 1, bpan1);
    COMPUTE(bpan0, accA, biasA, t0);
    __syncthreads();

    // ---- main loop: two-phase static-register pipeline ----
    int i = t0 + 1;
    bool lastA = true;
    while (i < t1) {
        {   // compute accB (tile i), epilogue accA (tile i-1)
            const unsigned char* bp = ((i - t0) & 1) ? bpan1 : bpan0;
            unsigned char*       st = ((i - t0) & 1) ? bpan0 : bpan1;
            if (i + 1 < t1) STAGE(i + 1, st);
            COMPUTE(bp, accB, biasB, i);
            EPI(accA, biasA);
            __syncthreads();
            lastA = false; ++i;
            if (i >= t1) break;
        }
        {   // compute accA (tile i), epilogue accB (tile i-1)
            const unsigned char* bp = ((i - t0) & 1) ? bpan1 : bpan0;
            unsigned char*       st = ((i - t0) & 1) ? bpan0 : bpan1;
            if (i + 1 < t1) STAGE(i + 1, st);
            COMPUTE(bp, accA, biasA, i);
            EPI(accB, biasB);
            __syncthreads();
            lastA = true; ++i;
        }
    }
    if (lastA) EPI(accA, biasA); else EPI(accB, biasB);

    // ---- one reduce + store per block ----
    const int cr = lane >> 4;
    #pragma unroll
    for (int rt = 0; rt < 4; ++rt)
        #pragma unroll
        for (int r = 0; r < 4; ++r) {
            const float v = row16_sum(rs[rt][r]);
            if (lm == 0)
                partial[(size_t)(grp * 4 + wc) * M_TOTAL + mw + rt * 16 + cr * 4 + r] = v;
        }
}

// ---------------------------------------------------------------------------
// Kernel 3: finalize. Target logit via tiny fp8 dot (frag-major permutation
// cancels in the dot) + log of the 32-stripe partial sum.
// ---------------------------------------------------------------------------
__global__ __launch_bounds__(256) void finalize_kernel(const unsigned char* __restrict__ zsb8,
                                                       const unsigned char* __restrict__ wt8,
                                                       const float* __restrict__ vb,
                                                       const int* __restrict__ y,
                                                       const float* __restrict__ partial,
                                                       float* __restrict__ out) {
    const int tid  = threadIdx.x;
    const int lane = tid & 63;
    const int rw   = lane >> 4;
    const int kl   = lane & 15;
    const int row  = blockIdx.x * 16 + (tid >> 6) * 4 + rw;
    const int yrow = y[row];

    u32x4 za = *(const u32x4*)(zsb8 + (size_t)row * E + kl * 16);
    u32x4 wa = *(const u32x4*)(wt8 + (size_t)yrow * E + kl * 16);
    float acc = 0.f;
    #pragma unroll
    for (int q = 0; q < 4; ++q) {
        f32x2 a0 = fp8x2_to_f32<false>(za[q]), b0 = fp8x2_to_f32<false>(wa[q]);
        f32x2 a1 = fp8x2_to_f32<true>(za[q]),  b1 = fp8x2_to_f32<true>(wa[q]);
        acc += a0[0] * b0[0] + a0[1] * b0[1] + a1[0] * b1[0] + a1[1] * b1[1];
    }
    const float logit = row16_sum(acc) + vb[yrow];

    float ps = partial[(size_t)kl * M_TOTAL + row] + partial[(size_t)(kl + 16) * M_TOTAL + row];
    const float tot = row16_sum(ps);

    if (kl == 0) out[row] = logit - logf(tot);
}

// ---------------------------------------------------------------------------
extern "C" void kernel_launch(void* const* d_in, const int* in_sizes, int n_in,
                              void* d_out, int out_size, void* d_ws, size_t ws_size,
                              hipStream_t stream) {
    const float* latent  = (const float*)d_in[0];
    const float* vocab_w = (const float*)d_in[1];
    const float* vocab_b = (const float*)d_in[2];
    const int*   zi      = (const int*)d_in[3];
    const int*   y       = (const int*)d_in[4];
    float* out = (float*)d_out;

    char* ws = (char*)d_ws;
    float*         partial = (float*)(ws);                             // 512 KB
    unsigned char* zsb8    = (unsigned char*)(ws + 524288);            // 1 MB
    unsigned char* wt8     = (unsigned char*)(ws + 524288 + 1048576);  // 8 MB

    hipLaunchKernelGGL(traj_transpose_kernel, dim3(BATCH + 4 * (V / 64)), dim3(512), 0, stream,
                       latent, zi, vocab_w, zsb8, wt8);
    hipLaunchKernelGGL(gemm_lse_kernel, dim3(32 * NGRP), dim3(512), 0, stream,
                       zsb8, wt8, vocab_b, partial);
    hipLaunchKernelGGL(finalize_kernel, dim3(M_TOTAL / 16), dim3(256), 0, stream,
                       zsb8, wt8, vocab_b, y, partial, out);
}